// Round 1
// baseline (17.743 us; speedup 1.0000x reference)
//
#include <hip/hip_runtime.h>

#define BATCH 4096
#define FEAT  2048
// 256 threads/block, FEAT/4 = 512 float4 -> 2 float4 per thread

__global__ __launch_bounds__(256) void center_loss_rows(
        const float* __restrict__ x,
        const int*   __restrict__ labels,
        const float* __restrict__ centers,
        float*       __restrict__ row_dist) {
    const int row = blockIdx.x;
    const int t   = threadIdx.x;

    const int lbl = labels[row];
    const float4* __restrict__ xr = (const float4*)(x + (size_t)row * FEAT);
    const float4* __restrict__ cr = (const float4*)(centers + (size_t)lbl * FEAT);

    float xs = 0.f, cs = 0.f, xc = 0.f;
#pragma unroll
    for (int i = 0; i < 2; ++i) {
        float4 xv = xr[t + i * 256];
        float4 cv = cr[t + i * 256];
        xs += xv.x * xv.x + xv.y * xv.y + xv.z * xv.z + xv.w * xv.w;
        cs += cv.x * cv.x + cv.y * cv.y + cv.z * cv.z + cv.w * cv.w;
        xc += xv.x * cv.x + xv.y * cv.y + xv.z * cv.z + xv.w * cv.w;
    }

    // wave-64 butterfly reduce
#pragma unroll
    for (int off = 32; off > 0; off >>= 1) {
        xs += __shfl_down(xs, off, 64);
        cs += __shfl_down(cs, off, 64);
        xc += __shfl_down(xc, off, 64);
    }

    __shared__ float sx[4], sc[4], sxc[4];
    const int wave = t >> 6;
    const int lane = t & 63;
    if (lane == 0) { sx[wave] = xs; sc[wave] = cs; sxc[wave] = xc; }
    __syncthreads();

    if (t == 0) {
        float X  = sx[0]  + sx[1]  + sx[2]  + sx[3];
        float C  = sc[0]  + sc[1]  + sc[2]  + sc[3];
        float XC = sxc[0] + sxc[1] + sxc[2] + sxc[3];
        float d = X + C - 2.0f * XC;
        d = fminf(fmaxf(d, 1e-12f), 1e12f);
        row_dist[row] = d;
    }
}

__global__ __launch_bounds__(256) void reduce_mean_kernel(
        const float* __restrict__ row_dist,
        float*       __restrict__ out) {
    const int t = threadIdx.x;
    float s = 0.f;
#pragma unroll
    for (int i = 0; i < BATCH / 256; ++i)
        s += row_dist[t + i * 256];

#pragma unroll
    for (int off = 32; off > 0; off >>= 1)
        s += __shfl_down(s, off, 64);

    __shared__ float sw[4];
    const int wave = t >> 6;
    const int lane = t & 63;
    if (lane == 0) sw[wave] = s;
    __syncthreads();

    if (t == 0) {
        float total = sw[0] + sw[1] + sw[2] + sw[3];
        out[0] = total * (1.0f / (float)BATCH);
    }
}

extern "C" void kernel_launch(void* const* d_in, const int* in_sizes, int n_in,
                              void* d_out, int out_size, void* d_ws, size_t ws_size,
                              hipStream_t stream) {
    const float* x       = (const float*)d_in[0];
    const int*   labels  = (const int*)d_in[1];
    const float* centers = (const float*)d_in[2];
    float* out = (float*)d_out;
    float* row_dist = (float*)d_ws;   // BATCH floats = 16 KB scratch

    center_loss_rows<<<BATCH, 256, 0, stream>>>(x, labels, centers, row_dist);
    reduce_mean_kernel<<<1, 256, 0, stream>>>(row_dist, out);
}

// Round 3
// 16.481 us; speedup vs baseline: 1.0766x; 1.0766x over previous
//
#include <hip/hip_runtime.h>

#define BATCH 4096
#define FEAT  2048

typedef float f32x4 __attribute__((ext_vector_type(4)));

// kernel 1: one block per batch row, 256 threads, 2 f32x4 per thread per array
__global__ __launch_bounds__(256) void center_loss_rows(
        const float* __restrict__ x,
        const int*   __restrict__ labels,
        const float* __restrict__ centers,
        float*       __restrict__ row_dist) {
    const int row = blockIdx.x;
    const int t   = threadIdx.x;

    const int lbl = labels[row];                      // uniform -> scalar load
    const f32x4* __restrict__ xr = (const f32x4*)(x + (size_t)row * FEAT) + t;
    const f32x4* __restrict__ cr = (const f32x4*)(centers + (size_t)lbl * FEAT) + t;

    // issue all four 16B loads before any arithmetic
    f32x4 xv0 = __builtin_nontemporal_load(xr);        // x: streamed, no reuse
    f32x4 xv1 = __builtin_nontemporal_load(xr + 256);
    f32x4 cv0 = cr[0];                                 // centers: keep cacheable (label dups)
    f32x4 cv1 = cr[256];

    // p = x.x + c.c - 2*x.c  (linear in lanes -> reduce a single scalar)
    float p = 0.f;
    p += xv0.x * xv0.x + xv0.y * xv0.y + xv0.z * xv0.z + xv0.w * xv0.w;
    p += xv1.x * xv1.x + xv1.y * xv1.y + xv1.z * xv1.z + xv1.w * xv1.w;
    p += cv0.x * cv0.x + cv0.y * cv0.y + cv0.z * cv0.z + cv0.w * cv0.w;
    p += cv1.x * cv1.x + cv1.y * cv1.y + cv1.z * cv1.z + cv1.w * cv1.w;
    p -= 2.0f * (xv0.x * cv0.x + xv0.y * cv0.y + xv0.z * cv0.z + xv0.w * cv0.w +
                 xv1.x * cv1.x + xv1.y * cv1.y + xv1.z * cv1.z + xv1.w * cv1.w);

    // wave-64 butterfly reduce (single value)
#pragma unroll
    for (int off = 32; off > 0; off >>= 1)
        p += __shfl_down(p, off, 64);

    __shared__ float sw[4];
    const int wave = t >> 6;
    if ((t & 63) == 0) sw[wave] = p;
    __syncthreads();

    if (t == 0) {
        float d = sw[0] + sw[1] + sw[2] + sw[3];
        d = fminf(fmaxf(d, 1e-12f), 1e12f);
        row_dist[row] = d;
    }
}

__global__ __launch_bounds__(256) void reduce_mean_kernel(
        const float* __restrict__ row_dist,
        float*       __restrict__ out) {
    const int t = threadIdx.x;
    float s = 0.f;
#pragma unroll
    for (int i = 0; i < BATCH / 256; ++i)
        s += row_dist[t + i * 256];

#pragma unroll
    for (int off = 32; off > 0; off >>= 1)
        s += __shfl_down(s, off, 64);

    __shared__ float sw[4];
    const int wave = t >> 6;
    if ((t & 63) == 0) sw[wave] = s;
    __syncthreads();

    if (t == 0)
        out[0] = (sw[0] + sw[1] + sw[2] + sw[3]) * (1.0f / (float)BATCH);
}

extern "C" void kernel_launch(void* const* d_in, const int* in_sizes, int n_in,
                              void* d_out, int out_size, void* d_ws, size_t ws_size,
                              hipStream_t stream) {
    const float* x       = (const float*)d_in[0];
    const int*   labels  = (const int*)d_in[1];
    const float* centers = (const float*)d_in[2];
    float* out = (float*)d_out;
    float* row_dist = (float*)d_ws;   // BATCH floats = 16 KB scratch

    center_loss_rows<<<BATCH, 256, 0, stream>>>(x, labels, centers, row_dist);
    reduce_mean_kernel<<<1, 256, 0, stream>>>(row_dist, out);
}

// Round 4
// 16.004 us; speedup vs baseline: 1.1086x; 1.0298x over previous
//
#include <hip/hip_runtime.h>

#define BATCH 4096
#define FEAT  2048

typedef float f32x4 __attribute__((ext_vector_type(4)));

// kernel 1: one WAVE per batch row. 1024 blocks x 256 threads (4 waves/block).
// Per lane: 8 f32x4 of x + 8 f32x4 of c (FEAT/4 = 512 float4 / 64 lanes = 8).
// No LDS, no __syncthreads — wave-local shuffle reduce only.
__global__ __launch_bounds__(256) void center_loss_rows(
        const float* __restrict__ x,
        const int*   __restrict__ labels,
        const float* __restrict__ centers,
        float*       __restrict__ row_dist) {
    const int wave = threadIdx.x >> 6;
    const int lane = threadIdx.x & 63;
    const int row  = (blockIdx.x << 2) | wave;

    const int lbl = labels[row];                      // wave-uniform -> scalar load
    const f32x4* __restrict__ xr = (const f32x4*)(x + (size_t)row * FEAT) + lane;
    const f32x4* __restrict__ cr = (const f32x4*)(centers + (size_t)lbl * FEAT) + lane;

    // issue all 16 loads before any arithmetic (max memory parallelism)
    f32x4 xv[8], cv[8];
#pragma unroll
    for (int i = 0; i < 8; ++i)
        xv[i] = __builtin_nontemporal_load(xr + (i << 6));   // x: streamed, no reuse
#pragma unroll
    for (int i = 0; i < 8; ++i)
        cv[i] = cr[i << 6];                                   // centers: cacheable (label dups)

    // dist = sum((x - c)^2)  ==  x.x + c.c - 2*x.c
    float p = 0.f;
#pragma unroll
    for (int i = 0; i < 8; ++i) {
        f32x4 d = xv[i] - cv[i];
        p += d.x * d.x + d.y * d.y + d.z * d.z + d.w * d.w;
    }

    // wave-64 butterfly reduce
#pragma unroll
    for (int off = 32; off > 0; off >>= 1)
        p += __shfl_down(p, off, 64);

    if (lane == 0) {
        float d = fminf(fmaxf(p, 1e-12f), 1e12f);
        row_dist[row] = d;
    }
}

// kernel 2: single block reduces the 4096 row dists -> mean
__global__ __launch_bounds__(256) void reduce_mean_kernel(
        const float* __restrict__ row_dist,
        float*       __restrict__ out) {
    const int t = threadIdx.x;
    const f32x4* __restrict__ rd = (const f32x4*)row_dist;

    float s = 0.f;
#pragma unroll
    for (int i = 0; i < BATCH / 4 / 256; ++i) {       // 4 f32x4 per thread
        f32x4 v = rd[t + i * 256];
        s += v.x + v.y + v.z + v.w;
    }

#pragma unroll
    for (int off = 32; off > 0; off >>= 1)
        s += __shfl_down(s, off, 64);

    __shared__ float sw[4];
    const int wave = t >> 6;
    if ((t & 63) == 0) sw[wave] = s;
    __syncthreads();

    if (t == 0)
        out[0] = (sw[0] + sw[1] + sw[2] + sw[3]) * (1.0f / (float)BATCH);
}

extern "C" void kernel_launch(void* const* d_in, const int* in_sizes, int n_in,
                              void* d_out, int out_size, void* d_ws, size_t ws_size,
                              hipStream_t stream) {
    const float* x       = (const float*)d_in[0];
    const int*   labels  = (const int*)d_in[1];
    const float* centers = (const float*)d_in[2];
    float* out = (float*)d_out;
    float* row_dist = (float*)d_ws;   // BATCH floats = 16 KB scratch

    center_loss_rows<<<BATCH / 4, 256, 0, stream>>>(x, labels, centers, row_dist);
    reduce_mean_kernel<<<1, 256, 0, stream>>>(row_dist, out);
}